// Round 13
// baseline (194.520 us; speedup 1.0000x reference)
//
#include <hip/hip_runtime.h>
#include <hip/hip_bf16.h>

// MoE MLP: x[1,2048,768] fp32, router_w[16,768], w1[768,12288], w2[12288,768]
// out[1,2048,768] fp32.  Experts: 8x512 + 8x1024, top-8, normalized.
// SPARSE GROUPED formulation: only the top-8 (token, expert) pairs are
// computed (reference is dense+masked; masked terms are exactly 0).
// Router builds per-expert token lists (cnt/toklist/combw); GEMM1 gathers
// X rows per expert and writes compact H_e; GEMM2 computes H_e @ W2_e and
// scatters into partial[slot][token] (slot = ordinal of expert within the
// token's 8 picks -> disjoint, deterministic); reduce sums the 8 slots.
// GEMM core = R8-proven counted-vmcnt 2-phase dbuf pipeline, BN=256
// (8 loads/tile: ph0 [B0..B3,A0,A2] gate vmcnt(2); ph1 [A1,A3] gate
// vmcnt(6)), XOR-swizzled LDS, setprio, affine pointers, static worst-case
// grids with uniform early-exit for graph capture.

#define T_TOK 2048
#define D_EMB 768
#define W_TOT 12288
#define N_EXP 16

typedef __attribute__((ext_vector_type(4))) float f32x4;
typedef __attribute__((ext_vector_type(8))) short bf16x8;

typedef __attribute__((address_space(1))) const unsigned int as1c_u32;
typedef __attribute__((address_space(3))) unsigned int as3_u32;

__device__ __forceinline__ void gload16(const void* g, void* l) {
  __builtin_amdgcn_global_load_lds((as1c_u32*)g, (as3_u32*)l, 16, 0, 0);
}

__device__ __forceinline__ unsigned short f2bf(float f) {
  __hip_bfloat16 h = __float2bfloat16(f);
  return *reinterpret_cast<unsigned short*>(&h);
}

__device__ __forceinline__ float gelu_f(float x) {
  // jax.nn.gelu default (approximate=True, tanh form)
  float x3 = x * x * x;
  float a = 0.7978845608028654f * __builtin_fmaf(0.044715f, x3, x);
  a = fminf(fmaxf(a, -20.f), 20.f);
  float e = __expf(-2.0f * a);
  float t = (1.0f - e) / (1.0f + e);
  return 0.5f * x * (1.0f + t);
}

// in fp32 [R][C] -> out bf16 [C][R]
__global__ __launch_bounds__(256) void transpose_cvt_kernel(
    const float* __restrict__ in, unsigned short* __restrict__ out, int R, int C) {
  __shared__ float tile[32][33];
  int c0 = blockIdx.x * 32;
  int r0 = blockIdx.y * 32;
  int i = threadIdx.x;
  {
    int r = i >> 3, c4 = (i & 7) * 4;
    float4 v = *(const float4*)(in + (size_t)(r0 + r) * C + c0 + c4);
    tile[r][c4 + 0] = v.x; tile[r][c4 + 1] = v.y;
    tile[r][c4 + 2] = v.z; tile[r][c4 + 3] = v.w;
  }
  __syncthreads();
  {
    int c = i >> 3, r4 = (i & 7) * 4;
    ushort4 o;
    o.x = f2bf(tile[r4 + 0][c]);
    o.y = f2bf(tile[r4 + 1][c]);
    o.z = f2bf(tile[r4 + 2][c]);
    o.w = f2bf(tile[r4 + 3][c]);
    *(ushort4*)(out + (size_t)(c0 + c) * R + r0 + r4) = o;
  }
}

// ------- router: emits xb = bf16(x), per-expert lists, comb weights -------

__global__ __launch_bounds__(256) void router_kernel(
    const float* __restrict__ x, const float* __restrict__ rw,
    unsigned short* __restrict__ xbout, int* __restrict__ toklist,
    float* __restrict__ combw, int* __restrict__ cnt) {
  int tid = threadIdx.x, lane = tid & 63, w = tid >> 6;
  int t = blockIdx.x * 4 + w;
  const float* xr = x + (size_t)t * D_EMB;
  float xv[12];
#pragma unroll
  for (int i = 0; i < 12; ++i) xv[i] = xr[lane + 64 * i];
#pragma unroll
  for (int i = 0; i < 12; ++i)
    xbout[(size_t)t * D_EMB + lane + 64 * i] = f2bf(xv[i]);
  float lg[16];
#pragma unroll
  for (int e = 0; e < 16; ++e) {
    const float* we = rw + (size_t)e * D_EMB;
    float p = 0.f;
#pragma unroll
    for (int i = 0; i < 12; ++i) p = __builtin_fmaf(xv[i], we[lane + 64 * i], p);
#pragma unroll
    for (int off = 32; off >= 1; off >>= 1) p += __shfl_xor(p, off, 64);
    lg[e] = p;
  }
  float mx = lg[0];
#pragma unroll
  for (int e = 1; e < 16; ++e) mx = fmaxf(mx, lg[e]);
  float ex[16];
#pragma unroll
  for (int e = 0; e < 16; ++e) ex[e] = __expf(lg[e] - mx);
  float selsum = 0.f, myval = 0.f;
  bool mysel = false;
#pragma unroll
  for (int e = 0; e < 16; ++e) {
    int rank = 0;
#pragma unroll
    for (int e2 = 0; e2 < 16; ++e2)
      rank += (ex[e2] > ex[e]) || (ex[e2] == ex[e] && e2 < e);
    bool sel = rank < 8;
    float v = sel ? ex[e] : 0.f;
    selsum += v;
    if (e == lane) { myval = v; mysel = sel; }
  }
  unsigned long long mask = __ballot(lane < 16 && mysel);
  if (lane < 16 && mysel) {
    int slot = __popcll(mask & ((1ull << lane) - 1));  // ordinal among picks
    int pos = atomicAdd(&cnt[lane], 1);
    toklist[lane * 2048 + pos] = t | (slot << 16);
    combw[lane * 2048 + pos] = myval / selsum;
  }
}

// --------- grouped 8-wave counted-vmcnt GEMM, 256x256 tile, BK=64 ---------
// MODE 0 (up-proj): A = gathered xb rows (lda 768, K=768), B = w1t rows
//   offe+cn0.. (ld 768). Epilogue: H_e[i][col] = gelu(acc)*combw (bf16).
// MODE 1 (down-proj): A = H_e (lda W, K=W), B = w2t rows cn0.. with K-window
//   at offe (ld 12288). Epilogue: scatter fp32 into partial[slot][tok].
// Worst-case grid 384 both; blocks with rm0 >= cntpad(e) exit uniformly.

template <int MODE>
__global__ __launch_bounds__(512, 2) void moe_gemm_kernel(
    const unsigned short* __restrict__ Abase,
    const unsigned short* __restrict__ Bbase,
    const int* __restrict__ toklist, const float* __restrict__ combw,
    const int* __restrict__ cnt, unsigned short* __restrict__ hbuf,
    float* __restrict__ partial, float* __restrict__ dump) {
  __shared__ __align__(16) char smem[131072];  // A dbuf 2x32KB | B dbuf 2x32KB

  const int tid = threadIdx.x;
  const int lane = tid & 63;
  const int wid = tid >> 6;
  const int wr = wid >> 2;        // 0..1  (M half: 128 rows)
  const int wc = wid & 3;         // 0..3  (N quarter: 64 cols)

  // ---- block decode: expert, W, offsets, tile coords ----
  int e, W, offe, mt, nt;
  int hb;                          // H base (elements) for this expert
  {
    int bid = blockIdx.x;
    if (MODE == 0) {
      if (bid < 128) {             // experts 0-7, width 512: 8 x (8M x 2N)
        e = bid >> 4; int r = bid & 15; mt = r >> 1; nt = r & 1;
        W = 512; offe = e * 512; hb = e * (2048 * 512);
      } else {                     // experts 8-15, width 1024: 8 x (8M x 4N)
        int b = bid - 128; int el = b >> 5; int r = b & 31; mt = r >> 2; nt = r & 3;
        e = el + 8; W = 1024; offe = 4096 + el * 1024;
        hb = 8 * (2048 * 512) + el * (2048 * 1024);
      }
    } else {
      int bb = bid;
      if (bid < 192) {             // experts 0-7: 8 x (8M x 3N)
        int el = bb / 24; e = el; W = 512; offe = el * 512; hb = el * (2048 * 512);
        bb -= el * 24;
      } else {
        bb -= 192; int el = bb / 24; e = el + 8; W = 1024;
        offe = 4096 + el * 1024; hb = 8 * (2048 * 512) + el * (2048 * 1024);
        bb -= el * 24;
      }
      mt = bb / 3; nt = bb - mt * 3;
    }
  }
  const int ce = cnt[e];
  const int cpad = (ce + 255) & ~255;
  const int rm0 = mt * 256;
  if (rm0 >= cpad) return;         // uniform early exit (worst-case grid)
  const int cn0 = nt * 256;
  const int ntiles = (MODE == 0) ? (D_EMB / 64) : (W >> 6);

  // ---- staging pointers (pre-swizzled source, rule #21); +128B per tile ----
  const int srow = tid >> 3;                         // 0..63 within 64-row chunk
  const int scol = ((tid & 7) * 16) ^ ((srow & 7) << 4);
  const char* pA[4];
#pragma unroll
  for (int j = 0; j < 4; ++j) {
    int i = rm0 + j * 64 + srow;
    size_t rowoff;
    if (MODE == 0) {
      int tok = (i < ce) ? (toklist[e * 2048 + i] & 0xFFFF) : 0;  // gather
      rowoff = (size_t)tok * D_EMB;
    } else {
      rowoff = (size_t)hb + (size_t)i * W;
    }
    pA[j] = (const char*)Abase + rowoff * 2 + scol;
  }
  const char* pB[4];
#pragma unroll
  for (int j = 0; j < 4; ++j) {
    int r = cn0 + j * 64 + srow;
    size_t rowoff = (MODE == 0) ? ((size_t)(offe + r) * D_EMB)
                                : ((size_t)r * W_TOT + offe);
    pB[j] = (const char*)Bbase + rowoff * 2 + scol;
  }

  // ---- LDS read bases (bytes; buffer-relative) ----
  const int lswz = (lane & 7) << 4;
  const int colk0 = (((lane >> 4) & 3) * 16) ^ lswz;
  const int colk1 = (64 + ((lane >> 4) & 3) * 16) ^ lswz;
  const int ab0 = wr * 16384 + (lane & 15) * 128 + colk0;
  const int ab1 = wr * 16384 + (lane & 15) * 128 + colk1;
  const int bb0 = wc * 8192 + (lane & 15) * 128 + colk0;
  const int bb1 = wc * 8192 + (lane & 15) * 128 + colk1;

  f32x4 acc[8][4];
#pragma unroll
  for (int m = 0; m < 8; ++m)
#pragma unroll
    for (int n = 0; n < 4; ++n) acc[m][n] = (f32x4){0.f, 0.f, 0.f, 0.f};

  // prologue: stage tile 0 into buffers 0 (same issue order as steady state)
#pragma unroll
  for (int j = 0; j < 4; ++j) gload16(pB[j], smem + 65536 + j * 8192 + wid * 1024);
  gload16(pA[0], smem + wid * 1024);
  gload16(pA[2], smem + 16384 + wid * 1024);
  gload16(pA[1], smem + 8192 + wid * 1024);
  gload16(pA[3], smem + 24576 + wid * 1024);
#pragma unroll
  for (int j = 0; j < 4; ++j) { pA[j] += 128; pB[j] += 128; }
  __builtin_amdgcn_sched_barrier(0);

  int aoff = 0, boff = 65536;
  bf16x8 af[4], ag[4], bfr[4], bgr[4];
  for (int t = 0; t < ntiles; ++t) {
    const int adst = aoff ^ 32768;
    const int bdst = boff ^ 32768;

    // ---- phase 0: m0-3 x all n ----
    asm volatile("s_waitcnt vmcnt(2)" ::: "memory");  // B0-3,A0,A2 of cur landed
    __builtin_amdgcn_s_barrier();
    __builtin_amdgcn_sched_barrier(0);
#pragma unroll
    for (int m = 0; m < 4; ++m) {
      af[m] = *(const bf16x8*)(smem + aoff + ab0 + m * 2048);
      ag[m] = *(const bf16x8*)(smem + aoff + ab1 + m * 2048);
    }
#pragma unroll
    for (int n = 0; n < 4; ++n) {
      bfr[n] = *(const bf16x8*)(smem + boff + bb0 + n * 2048);
      bgr[n] = *(const bf16x8*)(smem + boff + bb1 + n * 2048);
    }
    // stage tile t+1 (pointers already advanced; one-past-end is in-bounds
    // of the adjacent ws buffers and never read)
#pragma unroll
    for (int j = 0; j < 4; ++j) gload16(pB[j], smem + bdst + j * 8192 + wid * 1024);
    gload16(pA[0], smem + adst + wid * 1024);
    gload16(pA[2], smem + adst + 16384 + wid * 1024);
    __builtin_amdgcn_sched_barrier(0);
    __builtin_amdgcn_s_setprio(1);
#pragma unroll
    for (int m = 0; m < 4; ++m)
#pragma unroll
      for (int n = 0; n < 4; ++n) {
        acc[m][n] = __builtin_amdgcn_mfma_f32_16x16x32_bf16(af[m], bfr[n], acc[m][n], 0, 0, 0);
        acc[m][n] = __builtin_amdgcn_mfma_f32_16x16x32_bf16(ag[m], bgr[n], acc[m][n], 0, 0, 0);
      }
    __builtin_amdgcn_s_setprio(0);

    // ---- phase 1: m4-7 x all n ----
    asm volatile("s_waitcnt vmcnt(6)" ::: "memory");  // A1,A3 of cur landed
    __builtin_amdgcn_s_barrier();
    __builtin_amdgcn_sched_barrier(0);
#pragma unroll
    for (int m = 0; m < 4; ++m) {
      af[m] = *(const bf16x8*)(smem + aoff + ab0 + 8192 + m * 2048);
      ag[m] = *(const bf16x8*)(smem + aoff + ab1 + 8192 + m * 2048);
    }
    gload16(pA[1], smem + adst + 8192 + wid * 1024);
    gload16(pA[3], smem + adst + 24576 + wid * 1024);
    __builtin_amdgcn_sched_barrier(0);
    __builtin_amdgcn_s_setprio(1);
#pragma unroll
    for (int m = 0; m < 4; ++m)
#pragma unroll
      for (int n = 0; n < 4; ++n) {
        acc[4 + m][n] = __builtin_amdgcn_mfma_f32_16x16x32_bf16(af[m], bfr[n], acc[4 + m][n], 0, 0, 0);
        acc[4 + m][n] = __builtin_amdgcn_mfma_f32_16x16x32_bf16(ag[m], bgr[n], acc[4 + m][n], 0, 0, 0);
      }
    __builtin_amdgcn_s_setprio(0);

#pragma unroll
    for (int j = 0; j < 4; ++j) { pA[j] += 128; pB[j] += 128; }
    aoff = adst; boff = bdst;
  }

  asm volatile("s_waitcnt vmcnt(0)" ::: "memory");  // drain tail stages

  // ---- epilogue ----
  const int r0 = (lane >> 4) * 4;
  const int cl = lane & 15;
  if constexpr (MODE == 0) {
#pragma unroll
    for (int m = 0; m < 8; ++m) {
#pragma unroll
      for (int r = 0; r < 4; ++r) {
        int i = rm0 + wr * 128 + m * 16 + r0 + r;
        float wgt = (i < ce) ? combw[e * 2048 + i] : 0.f;
        unsigned short* hrow = hbuf + (size_t)hb + (size_t)i * W + cn0;
#pragma unroll
        for (int n = 0; n < 4; ++n)
          hrow[wc * 64 + n * 16 + cl] = f2bf(gelu_f(acc[m][n][r]) * wgt);
      }
    }
  } else {
#pragma unroll
    for (int m = 0; m < 8; ++m) {
#pragma unroll
      for (int r = 0; r < 4; ++r) {
        int i = rm0 + wr * 128 + m * 16 + r0 + r;
        int entry = toklist[e * 2048 + i];   // garbage if i>=ce (guarded)
        bool valid = (i < ce);
        int tok = entry & 0xFFFF;
        int slot = (entry >> 16) & 7;
        float* dst = valid
            ? partial + ((size_t)slot * 2048 + tok) * D_EMB + cn0
            : dump + cn0 - cn0;              // dump sink (768 floats)
        if (!valid) dst = dump;
#pragma unroll
        for (int n = 0; n < 4; ++n)
          dst[wc * 64 + n * 16 + cl] = acc[m][n][r];
      }
    }
  }
}

__global__ __launch_bounds__(256) void reduce_kernel(
    const float* __restrict__ partial, float* __restrict__ out) {
  int i = (blockIdx.x * 256 + threadIdx.x) * 4;
  if (i >= T_TOK * D_EMB) return;
  float4 s = *(const float4*)(partial + i);
#pragma unroll
  for (int sp = 1; sp < 8; ++sp) {
    float4 v = *(const float4*)(partial + (size_t)sp * T_TOK * D_EMB + i);
    s.x += v.x; s.y += v.y; s.z += v.z; s.w += v.w;
  }
  *(float4*)(out + i) = s;
}

// ---------------- launcher ----------------

extern "C" void kernel_launch(void* const* d_in, const int* in_sizes, int n_in,
                              void* d_out, int out_size, void* d_ws, size_t ws_size,
                              hipStream_t stream) {
  const float* x = (const float*)d_in[0];
  const float* router_w = (const float*)d_in[1];
  const float* w1 = (const float*)d_in[2];
  const float* w2 = (const float*)d_in[3];
  float* out = (float*)d_out;

  char* ws = (char*)d_ws;
  size_t off = 0;
  auto alloc = [&](size_t bytes) {
    char* p = ws + off;
    off += (bytes + 255) & ~(size_t)255;
    return p;
  };
  unsigned short* xb  = (unsigned short*)alloc((size_t)T_TOK * D_EMB * 2);
  unsigned short* w1t = (unsigned short*)alloc((size_t)W_TOT * D_EMB * 2);
  unsigned short* w2t = (unsigned short*)alloc((size_t)D_EMB * W_TOT * 2);
  unsigned short* hbuf = (unsigned short*)alloc((size_t)T_TOK * W_TOT * 2);  // worst-case compact H
  int*   toklist = (int*)alloc((size_t)N_EXP * 2048 * 4);
  float* combw   = (float*)alloc((size_t)N_EXP * 2048 * 4);
  int*   cnt     = (int*)alloc(64);
  float* dump    = (float*)alloc(768 * 4);
  float* partial = (float*)alloc((size_t)8 * T_TOK * D_EMB * 4);

  hipMemsetAsync(cnt, 0, 64, stream);
  transpose_cvt_kernel<<<dim3(W_TOT / 32, D_EMB / 32), 256, 0, stream>>>(w1, w1t, D_EMB, W_TOT);
  transpose_cvt_kernel<<<dim3(D_EMB / 32, W_TOT / 32), 256, 0, stream>>>(w2, w2t, W_TOT, D_EMB);
  router_kernel<<<T_TOK / 4, 256, 0, stream>>>(x, router_w, xb, toklist, combw, cnt);

  // grouped up-proj: worst-case grid 384 (128 for w512 experts + 256 for w1024)
  moe_gemm_kernel<0><<<384, 512, 0, stream>>>(
      xb, w1t, toklist, combw, cnt, hbuf, nullptr, nullptr);

  // grouped down-proj: worst-case grid 384 (192 + 192), scatter to partial
  moe_gemm_kernel<1><<<384, 512, 0, stream>>>(
      hbuf, w2t, toklist, nullptr, cnt, nullptr, partial, dump);

  reduce_kernel<<<(T_TOK * D_EMB) / 1024, 256, 0, stream>>>(partial, out);
}

// Round 14
// 156.629 us; speedup vs baseline: 1.2419x; 1.2419x over previous
//
#include <hip/hip_runtime.h>
#include <hip/hip_bf16.h>

// MoE MLP: x[1,2048,768] fp32, router_w[16,768], w1[768,12288], w2[12288,768]
// out[1,2048,768] fp32.  Experts: 8x512 + 8x1024, top-8, normalized.
// Dense bf16 GEMMs (reference is dense+masked); comb folded into H.
// GEMM core: 256x256 tile, BK=32, RING-3 LDS (96KB), DEPTH-2 prefetch
// (8 loads / 64KB outstanding per CU), R8-proven gate: per-wave vmcnt(4) +
// one s_barrier per tile (collective-landing proof identical to R8).
// R11-verified consistent XOR swizzle. XCD maps from R8. 3x unrolled loop
// so ring indices are compile-time.

#define T_TOK 2048
#define D_EMB 768
#define W_TOT 12288
#define N_EXP 16

typedef __attribute__((ext_vector_type(4))) float f32x4;
typedef __attribute__((ext_vector_type(8))) short bf16x8;

typedef __attribute__((address_space(1))) const unsigned int as1c_u32;
typedef __attribute__((address_space(3))) unsigned int as3_u32;

__device__ __forceinline__ void gload16(const void* g, void* l) {
  __builtin_amdgcn_global_load_lds((as1c_u32*)g, (as3_u32*)l, 16, 0, 0);
}

__device__ __forceinline__ unsigned short f2bf(float f) {
  __hip_bfloat16 h = __float2bfloat16(f);
  return *reinterpret_cast<unsigned short*>(&h);
}

__device__ __forceinline__ float gelu_f(float x) {
  // jax.nn.gelu default (approximate=True, tanh form)
  float x3 = x * x * x;
  float a = 0.7978845608028654f * __builtin_fmaf(0.044715f, x3, x);
  a = fminf(fmaxf(a, -20.f), 20.f);
  float e = __expf(-2.0f * a);
  float t = (1.0f - e) / (1.0f + e);
  return 0.5f * x * (1.0f + t);
}

// in fp32 [R][C] -> out bf16 [C][R]
__global__ __launch_bounds__(256) void transpose_cvt_kernel(
    const float* __restrict__ in, unsigned short* __restrict__ out, int R, int C) {
  __shared__ float tile[32][33];
  int c0 = blockIdx.x * 32;
  int r0 = blockIdx.y * 32;
  int i = threadIdx.x;
  {
    int r = i >> 3, c4 = (i & 7) * 4;
    float4 v = *(const float4*)(in + (size_t)(r0 + r) * C + c0 + c4);
    tile[r][c4 + 0] = v.x; tile[r][c4 + 1] = v.y;
    tile[r][c4 + 2] = v.z; tile[r][c4 + 3] = v.w;
  }
  __syncthreads();
  {
    int c = i >> 3, r4 = (i & 7) * 4;
    ushort4 o;
    o.x = f2bf(tile[r4 + 0][c]);
    o.y = f2bf(tile[r4 + 1][c]);
    o.z = f2bf(tile[r4 + 2][c]);
    o.w = f2bf(tile[r4 + 3][c]);
    *(ushort4*)(out + (size_t)(c0 + c) * R + r0 + r4) = o;
  }
}

// ---------------- router (also emits xb = bf16(x)) ----------------

__global__ __launch_bounds__(256) void router_kernel(
    const float* __restrict__ x, const float* __restrict__ rw,
    float* __restrict__ comb, unsigned short* __restrict__ xbout) {
  int tid = threadIdx.x, lane = tid & 63, w = tid >> 6;
  int t = blockIdx.x * 4 + w;
  const float* xr = x + (size_t)t * D_EMB;
  float xv[12];
#pragma unroll
  for (int i = 0; i < 12; ++i) xv[i] = xr[lane + 64 * i];
#pragma unroll
  for (int i = 0; i < 12; ++i)
    xbout[(size_t)t * D_EMB + lane + 64 * i] = f2bf(xv[i]);
  float lg[16];
#pragma unroll
  for (int e = 0; e < 16; ++e) {
    const float* we = rw + (size_t)e * D_EMB;
    float p = 0.f;
#pragma unroll
    for (int i = 0; i < 12; ++i) p = __builtin_fmaf(xv[i], we[lane + 64 * i], p);
#pragma unroll
    for (int off = 32; off >= 1; off >>= 1) p += __shfl_xor(p, off, 64);
    lg[e] = p;
  }
  float mx = lg[0];
#pragma unroll
  for (int e = 1; e < 16; ++e) mx = fmaxf(mx, lg[e]);
  float ex[16];
#pragma unroll
  for (int e = 0; e < 16; ++e) ex[e] = __expf(lg[e] - mx);
  float selsum = 0.f, myval = 0.f;
#pragma unroll
  for (int e = 0; e < 16; ++e) {
    int rank = 0;
#pragma unroll
    for (int e2 = 0; e2 < 16; ++e2)
      rank += (ex[e2] > ex[e]) || (ex[e2] == ex[e] && e2 < e);
    bool sel = rank < 8;
    float v = sel ? ex[e] : 0.f;
    selsum += v;
    if (e == lane) myval = v;
  }
  if (lane < 16) comb[(size_t)t * N_EXP + lane] = myval / selsum;
}

// -------- 8-wave ring-3 depth-2 GEMM, 256x256 tile, BK=32 --------
// A row-major [M][lda], B N-major [N][ldb] (bf16, K contiguous).
// 8 waves = 2(M) x 4(N); per-wave 128x64 out; acc[8][4].
// LDS: A ring 3x16KB @0, B ring 3x16KB @49152. Tile t uses buf t%3,
// stages tile t+2 into buf (t+2)%3 AFTER the tile-top barrier (which
// retires all reads of that buf from tile t-1). Gate: per-wave vmcnt(4)
// (own t-loads landed; t+1's 4 stay in flight) then s_barrier -> collective.
// MAP: 0 = gemm1 XCD-owns-6-N-panels (grid 384), 1 = gemm2 XCD=zt (grid 192).
// EPI: 1 = gelu*comb -> bf16 H, 0 = fp32 partial.

#define TILE(TT)                                                               \
  {                                                                            \
    asm volatile("s_waitcnt vmcnt(4)" ::: "memory");                           \
    __builtin_amdgcn_s_barrier();                                              \
    __builtin_amdgcn_sched_barrier(0);                                         \
    _Pragma("unroll")                                                          \
    for (int m = 0; m < 8; ++m)                                                \
      a[m] = *(const bf16x8*)(smem + (TT) * 16384 + abase + m * 1024);         \
    _Pragma("unroll")                                                          \
    for (int n = 0; n < 4; ++n)                                                \
      b[n] = *(const bf16x8*)(smem + 49152 + (TT) * 16384 + bbase + n * 1024); \
    gload16(pA0, smem + (((TT) + 2) % 3) * 16384 + wid * 1024);                \
    gload16(pA1, smem + (((TT) + 2) % 3) * 16384 + 8192 + wid * 1024);         \
    gload16(pB0, smem + 49152 + (((TT) + 2) % 3) * 16384 + wid * 1024);        \
    gload16(pB1, smem + 49152 + (((TT) + 2) % 3) * 16384 + 8192 + wid * 1024); \
    pA0 += 64; pA1 += 64; pB0 += 64; pB1 += 64;                                \
    __builtin_amdgcn_sched_barrier(0);                                         \
    __builtin_amdgcn_s_setprio(1);                                             \
    _Pragma("unroll")                                                          \
    for (int m = 0; m < 8; ++m)                                                \
      _Pragma("unroll")                                                        \
      for (int n = 0; n < 4; ++n)                                              \
        acc[m][n] = __builtin_amdgcn_mfma_f32_16x16x32_bf16(                   \
            a[m], b[n], acc[m][n], 0, 0, 0);                                   \
    __builtin_amdgcn_s_setprio(0);                                             \
  }

template <int EPI, int MAP>
__global__ __launch_bounds__(512, 2) void gemm_kernel(
    const unsigned short* __restrict__ Ag, const unsigned short* __restrict__ Bg,
    int lda, int ldb, int ntiles, int kchunk,
    const float* __restrict__ comb, unsigned short* __restrict__ hout,
    float* __restrict__ pout) {
  __shared__ __align__(16) char smem[98304];  // A ring 3x16KB | B ring 3x16KB

  const int tid = threadIdx.x;
  const int lane = tid & 63;
  const int wid = tid >> 6;
  const int wr = wid >> 2;        // 0..1  (M half: 128 rows)
  const int wc = wid & 3;         // 0..3  (N quarter: 64 cols)

  int mt, nt, zt;
  {
    int bid = blockIdx.x;
    if (MAP == 0) {               // gemm1: XCD owns 6 N-panels, M fastest
      int xcd = bid & 7, r = bid >> 3;        // r in 0..47
      nt = xcd * 6 + (r >> 3); mt = r & 7; zt = 0;
    } else {                      // gemm2: XCD = K-split
      zt = bid & 7; int r = bid >> 3;         // r in 0..23
      nt = r % 3; mt = r / 3;
    }
  }
  const int rm0 = mt * 256;
  const int cn0 = nt * 256;
  const int kbeg = zt * kchunk;

  // ---- affine staging pointers (pre-swizzled source, rule #21) ----
  // gload j covers LDS bytes j*8192 + tid*16: row = j*128 + (tid>>2),
  // slot = tid&3; source slot = (tid&3) ^ (row&3), row&3 = (tid>>2)&3.
  const int srow = tid >> 2;
  const int scol = ((tid & 3) ^ (srow & 3)) << 4;
  const char* pA0 = (const char*)Ag + ((size_t)(rm0 + srow) * lda + kbeg) * 2 + scol;
  const char* pA1 = (const char*)Ag + ((size_t)(rm0 + 128 + srow) * lda + kbeg) * 2 + scol;
  const char* pB0 = (const char*)Bg + ((size_t)(cn0 + srow) * ldb + kbeg) * 2 + scol;
  const char* pB1 = (const char*)Bg + ((size_t)(cn0 + 128 + srow) * ldb + kbeg) * 2 + scol;

  // ---- LDS read bases: 64B rows; slot = (lane>>4) ^ (row&3), row&3=lane&3 ----
  const int colsw = ((lane >> 4) ^ (lane & 3)) << 4;
  const int abase = (wr * 128 + (lane & 15)) * 64 + colsw;          // + m*1024
  const int bbase = (wc * 64 + (lane & 15)) * 64 + colsw;           // + n*1024

  f32x4 acc[8][4];
#pragma unroll
  for (int m = 0; m < 8; ++m)
#pragma unroll
    for (int n = 0; n < 4; ++n) acc[m][n] = (f32x4){0.f, 0.f, 0.f, 0.f};

  // prologue: stage tile 0 -> buf0, tile 1 -> buf1 (same per-tile order)
  gload16(pA0, smem + wid * 1024);
  gload16(pA1, smem + 8192 + wid * 1024);
  gload16(pB0, smem + 49152 + wid * 1024);
  gload16(pB1, smem + 49152 + 8192 + wid * 1024);
  gload16(pA0 + 64, smem + 16384 + wid * 1024);
  gload16(pA1 + 64, smem + 16384 + 8192 + wid * 1024);
  gload16(pB0 + 64, smem + 49152 + 16384 + wid * 1024);
  gload16(pB1 + 64, smem + 49152 + 16384 + 8192 + wid * 1024);
  pA0 += 128; pA1 += 128; pB0 += 128; pB1 += 128;   // now at tile 2
  __builtin_amdgcn_sched_barrier(0);

  bf16x8 a[8], b[4];
  const int nit = ntiles / 3;     // ntiles: 24 (gemm1) / 48 (gemm2)
  for (int i = 0; i < nit; ++i) {
    TILE(0)
    TILE(1)
    TILE(2)
  }

  asm volatile("s_waitcnt vmcnt(0)" ::: "memory");  // drain tail stages
  __syncthreads();

  // ---- epilogue ----
  const int r0 = (lane >> 4) * 4;
  const int cl = lane & 15;
  if constexpr (EPI == 1) {
    float* Cwf = (float*)smem;   // reuse staging LDS: [256 rows][16 experts]
    {
      int row = tid >> 1, c8 = (tid & 1) * 8;
      const float* s = comb + (size_t)(rm0 + row) * N_EXP + c8;
      *(float4*)&Cwf[row * 16 + c8] = *(const float4*)s;
      *(float4*)&Cwf[row * 16 + c8 + 4] = *(const float4*)(s + 4);
    }
    __syncthreads();
#pragma unroll
    for (int n = 0; n < 4; ++n) {
      int colg = cn0 + wc * 64 + n * 16 + cl;
      int e = (colg < 4096) ? (colg >> 9) : (8 + ((colg - 4096) >> 10));
#pragma unroll
      for (int m = 0; m < 8; ++m) {
        int rl = wr * 128 + m * 16 + r0;
#pragma unroll
        for (int r = 0; r < 4; ++r) {
          float v = gelu_f(acc[m][n][r]) * Cwf[(rl + r) * 16 + e];
          hout[(size_t)(rm0 + rl + r) * W_TOT + colg] = f2bf(v);
        }
      }
    }
  } else {
    float* pz = pout + (size_t)zt * T_TOK * D_EMB;
#pragma unroll
    for (int n = 0; n < 4; ++n) {
      int colg = cn0 + wc * 64 + n * 16 + cl;
#pragma unroll
      for (int m = 0; m < 8; ++m) {
        int rl = wr * 128 + m * 16 + r0;
#pragma unroll
        for (int r = 0; r < 4; ++r)
          pz[(size_t)(rm0 + rl + r) * D_EMB + colg] = acc[m][n][r];
      }
    }
  }
}

__global__ __launch_bounds__(256) void reduce_kernel(
    const float* __restrict__ partial, float* __restrict__ out, int splits) {
  int i = (blockIdx.x * 256 + threadIdx.x) * 4;
  if (i >= T_TOK * D_EMB) return;
  float4 s = *(const float4*)(partial + i);
  for (int sp = 1; sp < splits; ++sp) {
    float4 v = *(const float4*)(partial + (size_t)sp * T_TOK * D_EMB + i);
    s.x += v.x; s.y += v.y; s.z += v.z; s.w += v.w;
  }
  *(float4*)(out + i) = s;
}

// ---------------- launcher ----------------

extern "C" void kernel_launch(void* const* d_in, const int* in_sizes, int n_in,
                              void* d_out, int out_size, void* d_ws, size_t ws_size,
                              hipStream_t stream) {
  const float* x = (const float*)d_in[0];
  const float* router_w = (const float*)d_in[1];
  const float* w1 = (const float*)d_in[2];
  const float* w2 = (const float*)d_in[3];
  float* out = (float*)d_out;

  char* ws = (char*)d_ws;
  size_t off = 0;
  auto alloc = [&](size_t bytes) {
    char* p = ws + off;
    off += (bytes + 255) & ~(size_t)255;
    return p;
  };
  unsigned short* xb  = (unsigned short*)alloc((size_t)T_TOK * D_EMB * 2);
  unsigned short* w1t = (unsigned short*)alloc((size_t)W_TOT * D_EMB * 2);
  unsigned short* w2t = (unsigned short*)alloc((size_t)D_EMB * W_TOT * 2);
  unsigned short* h   = (unsigned short*)alloc((size_t)T_TOK * W_TOT * 2);
  float* comb         = (float*)alloc((size_t)T_TOK * N_EXP * 4);

  const int splits = 8;                     // grid 192; kchunk 1536 (48 tiles)
  float* partial = (float*)alloc((size_t)splits * T_TOK * D_EMB * 4);
  int kchunk = W_TOT / splits;

  transpose_cvt_kernel<<<dim3(W_TOT / 32, D_EMB / 32), 256, 0, stream>>>(w1, w1t, D_EMB, W_TOT);
  transpose_cvt_kernel<<<dim3(D_EMB / 32, W_TOT / 32), 256, 0, stream>>>(w2, w2t, W_TOT, D_EMB);
  router_kernel<<<T_TOK / 4, 256, 0, stream>>>(x, router_w, comb, xb);

  // GEMM1: H = gelu(X W1) * comb ; grid 384 = 8 XCD x (6 N x 8 M); 24 tiles
  gemm_kernel<1, 0><<<384, 512, 0, stream>>>(
      xb, w1t, D_EMB, D_EMB, D_EMB / 32, D_EMB, comb, h, nullptr);

  // GEMM2: OUT = H W2 ; grid 192 = 8 splits x (3 N x 8 M); 48 tiles
  gemm_kernel<0, 1><<<192, 512, 0, stream>>>(
      h, w2t, W_TOT, W_TOT, kchunk / 32, kchunk, nullptr, nullptr, partial);

  reduce_kernel<<<(T_TOK * D_EMB) / 1024, 256, 0, stream>>>(partial, out, splits);
}